// Round 1
// baseline (1591.983 us; speedup 1.0000x reference)
//
#include <hip/hip_runtime.h>

#define NNODES 50000
#define NEDGES 1600000
#define FNODE 32
#define FEDGE 8
#define HIDD 256
#define NGRAPH 64
#define GDIM 16
#define NACT 64
#define FEATD (HIDD + GDIM) // 272

// ---------------- CSR build ----------------

__global__ void k_zero_i32(int* __restrict__ p, int n) {
  int i = blockIdx.x * blockDim.x + threadIdx.x;
  if (i < n) p[i] = 0;
}

__global__ void k_hist(const int* __restrict__ dst, int* __restrict__ off) {
  int e = blockIdx.x * blockDim.x + threadIdx.x;
  if (e < NEDGES) atomicAdd(&off[dst[e] + 1], 1);
}

__global__ void k_scan1(int* __restrict__ data, int n, int* __restrict__ sums) {
  __shared__ int buf[1024];
  int gid = blockIdx.x * 1024 + threadIdx.x;
  int v = (gid < n) ? data[gid] : 0;
  buf[threadIdx.x] = v;
  __syncthreads();
  for (int d = 1; d < 1024; d <<= 1) {
    int t = (threadIdx.x >= d) ? buf[threadIdx.x - d] : 0;
    __syncthreads();
    buf[threadIdx.x] += t;
    __syncthreads();
  }
  if (gid < n) data[gid] = buf[threadIdx.x];
  if (threadIdx.x == 1023) sums[blockIdx.x] = buf[1023];
}

__global__ void k_scan2(int* __restrict__ sums, int nb) {
  int run = 0;
  for (int i = 0; i < nb; ++i) { run += sums[i]; sums[i] = run; }
}

__global__ void k_scan3(int* __restrict__ data, int n, const int* __restrict__ sums) {
  int gid = blockIdx.x * 1024 + threadIdx.x;
  if (blockIdx.x > 0 && gid < n) data[gid] += sums[blockIdx.x - 1];
}

__global__ void k_copy_i32(const int* __restrict__ a, int* __restrict__ b, int n) {
  int i = blockIdx.x * blockDim.x + threadIdx.x;
  if (i < n) b[i] = a[i];
}

__global__ void k_scatter(const int* __restrict__ src, const int* __restrict__ dst,
                          int* __restrict__ cur, int* __restrict__ csr_src,
                          int* __restrict__ csr_eid) {
  int e = blockIdx.x * blockDim.x + threadIdx.x;
  if (e >= NEDGES) return;
  int d = dst[e];
  int pos = atomicAdd(&cur[d], 1);
  csr_src[pos] = src[e];
  csr_eid[pos] = e;
}

// ---------------- Layer 0 edge pull (d=32) ----------------
// one wave per node; lanes 0-31 handle even edges' 32 cols, lanes 32-63 odd edges

__global__ void k_edge32(const float* __restrict__ x, const float* __restrict__ ea,
                         const float* __restrict__ We0, const int* __restrict__ off,
                         const int* __restrict__ csr_src, const int* __restrict__ csr_eid,
                         float* __restrict__ t0) {
  int wid = (blockIdx.x * blockDim.x + threadIdx.x) >> 6;
  if (wid >= NNODES) return;
  int lane = threadIdx.x & 63;
  int j = lane >> 5;
  int c = lane & 31;
  float we[FEDGE];
#pragma unroll
  for (int k = 0; k < FEDGE; ++k) we[k] = We0[k * FNODE + c];
  int s0 = off[wid], s1 = off[wid + 1];
  float acc = 0.f;
  for (int e = s0 + j; e < s1; e += 2) {
    int s = csr_src[e];
    int id = csr_eid[e];
    float hs = x[s * FNODE + c];
    const float4 e0 = *(const float4*)&ea[(size_t)id * FEDGE];
    const float4 e1 = *(const float4*)&ea[(size_t)id * FEDGE + 4];
    float pr = hs;
    pr = fmaf(e0.x, we[0], pr);
    pr = fmaf(e0.y, we[1], pr);
    pr = fmaf(e0.z, we[2], pr);
    pr = fmaf(e0.w, we[3], pr);
    pr = fmaf(e1.x, we[4], pr);
    pr = fmaf(e1.y, we[5], pr);
    pr = fmaf(e1.z, we[6], pr);
    pr = fmaf(e1.w, we[7], pr);
    acc += fmaxf(pr, 0.f);
  }
  acc += __shfl_xor(acc, 32);
  if (j == 0) t0[wid * FNODE + c] = x[wid * FNODE + c] + acc;
}

// ---------------- Layers 1-3 edge pull (d=256) ----------------
// one wave per node; lane owns 4 contiguous cols (float4); We slice in 32 VGPRs

__global__ void k_edge256(const float* __restrict__ h, const float* __restrict__ ea,
                          const float* __restrict__ Wel, const int* __restrict__ off,
                          const int* __restrict__ csr_src, const int* __restrict__ csr_eid,
                          float* __restrict__ t) {
  int wid = (blockIdx.x * blockDim.x + threadIdx.x) >> 6;
  if (wid >= NNODES) return;
  int lane = threadIdx.x & 63;
  int c = lane * 4;
  float4 wef[FEDGE];
#pragma unroll
  for (int k = 0; k < FEDGE; ++k) wef[k] = *(const float4*)&Wel[k * HIDD + c];
  int s0 = off[wid], s1 = off[wid + 1];
  float4 acc = {0.f, 0.f, 0.f, 0.f};
  for (int e = s0; e < s1; ++e) {
    int s = csr_src[e];
    int id = csr_eid[e];
    const float4 hs = *(const float4*)&h[(size_t)s * HIDD + c];
    const float4 e0 = *(const float4*)&ea[(size_t)id * FEDGE];
    const float4 e1 = *(const float4*)&ea[(size_t)id * FEDGE + 4];
    float4 pr = hs;
#define ACCK(ev, kk)                              \
    pr.x = fmaf(ev, wef[kk].x, pr.x);             \
    pr.y = fmaf(ev, wef[kk].y, pr.y);             \
    pr.z = fmaf(ev, wef[kk].z, pr.z);             \
    pr.w = fmaf(ev, wef[kk].w, pr.w);
    ACCK(e0.x, 0) ACCK(e0.y, 1) ACCK(e0.z, 2) ACCK(e0.w, 3)
    ACCK(e1.x, 4) ACCK(e1.y, 5) ACCK(e1.z, 6) ACCK(e1.w, 7)
#undef ACCK
    acc.x += fmaxf(pr.x, 0.f);
    acc.y += fmaxf(pr.y, 0.f);
    acc.z += fmaxf(pr.z, 0.f);
    acc.w += fmaxf(pr.w, 0.f);
  }
  const float4 self = *(const float4*)&h[(size_t)wid * HIDD + c];
  float4 o;
  o.x = self.x + acc.x;
  o.y = self.y + acc.y;
  o.z = self.z + acc.z;
  o.w = self.w + acc.w;
  *(float4*)&t[(size_t)wid * HIDD + c] = o;
}

// ---------------- Node update GEMM: out = relu(T @ W + b), out may alias T ----

template <int K>
__global__ __launch_bounds__(256) void k_gemm_relu(const float* T, const float* __restrict__ W,
                                                   const float* __restrict__ bias, float* out,
                                                   int nrows) {
  __shared__ float tl[32][K];
  const int r0 = blockIdx.x * 32;
  const int tid = threadIdx.x;
  const int KV = K / 4;
  for (int i = tid; i < 32 * KV; i += 256) {
    int row = i / KV;
    int kk = (i - row * KV) * 4;
    float4 v = {0.f, 0.f, 0.f, 0.f};
    if (r0 + row < nrows) v = *(const float4*)&T[(size_t)(r0 + row) * K + kk];
    *(float4*)&tl[row][kk] = v;
  }
  __syncthreads();
  const int c = (tid & 63) * 4;
  const int rg = (tid >> 6) * 8;
  float4 acc[8];
#pragma unroll
  for (int r = 0; r < 8; ++r) acc[r] = make_float4(0.f, 0.f, 0.f, 0.f);
  for (int k = 0; k < K; ++k) {
    const float4 w = *(const float4*)&W[k * HIDD + c];
#pragma unroll
    for (int r = 0; r < 8; ++r) {
      float tv = tl[rg + r][k];
      acc[r].x = fmaf(tv, w.x, acc[r].x);
      acc[r].y = fmaf(tv, w.y, acc[r].y);
      acc[r].z = fmaf(tv, w.z, acc[r].z);
      acc[r].w = fmaf(tv, w.w, acc[r].w);
    }
  }
  const float4 bb = *(const float4*)&bias[c];
#pragma unroll
  for (int r = 0; r < 8; ++r) {
    int row = r0 + rg + r;
    if (row < nrows) {
      float4 o;
      o.x = fmaxf(acc[r].x + bb.x, 0.f);
      o.y = fmaxf(acc[r].y + bb.y, 0.f);
      o.z = fmaxf(acc[r].z + bb.z, 0.f);
      o.w = fmaxf(acc[r].w + bb.w, 0.f);
      *(float4*)&out[(size_t)row * HIDD + c] = o;
    }
  }
}

// ---------------- Mean pool per graph (batch sorted) ----------------

__global__ void k_pool(const float* __restrict__ h, const int* __restrict__ batch,
                       const float* __restrict__ gf, float* __restrict__ feats) {
  int b = blockIdx.x;
  __shared__ int srange[2];
  if (threadIdx.x < 2) {
    int target = b + threadIdx.x;
    int lo = 0, hi = NNODES;
    while (lo < hi) {
      int mid = (lo + hi) >> 1;
      if (batch[mid] < target) lo = mid + 1; else hi = mid;
    }
    srange[threadIdx.x] = lo;
  }
  __syncthreads();
  int s = srange[0], e = srange[1];
  int col = threadIdx.x; // 256 threads = 256 cols
  float acc = 0.f;
  for (int n = s; n < e; ++n) acc += h[(size_t)n * HIDD + col];
  float cnt = fmaxf((float)(e - s), 1.0f);
  feats[b * FEATD + col] = acc / cnt;
  if (threadIdx.x < GDIM) feats[b * FEATD + HIDD + threadIdx.x] = gf[b * GDIM + threadIdx.x];
}

// ---------------- Heads: logits [B,64] then value [B] ----------------

__global__ void k_heads(const float* __restrict__ feats, const float* __restrict__ Wp,
                        const float* __restrict__ bp, const float* __restrict__ Wv,
                        const float* __restrict__ bv, float* __restrict__ out) {
  int b = blockIdx.x;
  int t = threadIdx.x; // 64 threads = 1 wave
  __shared__ float f[FEATD];
  for (int i = t; i < FEATD; i += 64) f[i] = feats[b * FEATD + i];
  __syncthreads();
  float acc = bp[t];
  for (int k = 0; k < FEATD; ++k) acc = fmaf(f[k], Wp[k * NACT + t], acc);
  out[b * NACT + t] = acc;
  float pv = 0.f;
  for (int k = t; k < FEATD; k += 64) pv = fmaf(f[k], Wv[k], pv);
#pragma unroll
  for (int d = 32; d > 0; d >>= 1) pv += __shfl_down(pv, d);
  if (t == 0) out[NGRAPH * NACT + b] = pv + bv[0];
}

// ---------------- launch ----------------

extern "C" void kernel_launch(void* const* d_in, const int* in_sizes, int n_in,
                              void* d_out, int out_size, void* d_ws, size_t ws_size,
                              hipStream_t stream) {
  const float* x   = (const float*)d_in[0];
  const float* ea  = (const float*)d_in[1];
  const float* gf  = (const float*)d_in[2];
  const float* We0 = (const float*)d_in[3];
  const float* W0  = (const float*)d_in[4];
  const float* b0  = (const float*)d_in[5];
  const float* We  = (const float*)d_in[6];
  const float* W   = (const float*)d_in[7];
  const float* bb  = (const float*)d_in[8];
  const float* Wp  = (const float*)d_in[9];
  const float* bp  = (const float*)d_in[10];
  const float* Wv  = (const float*)d_in[11];
  const float* bv  = (const float*)d_in[12];
  const int* eidx  = (const int*)d_in[13];
  const int* batch = (const int*)d_in[14];
  const int* esrc = eidx;
  const int* edst = eidx + NEDGES;

  char* w = (char*)d_ws;
  size_t p = 0;
  auto take = [&](size_t bytes) {
    size_t r = p;
    p += (bytes + 255) & ~(size_t)255;
    return r;
  };
  int* off      = (int*)(w + take((NNODES + 1) * 4));
  int* cur      = (int*)(w + take(NNODES * 4));
  int* sums     = (int*)(w + take(1024));
  int* csr_src  = (int*)(w + take((size_t)NEDGES * 4));
  int* csr_eid  = (int*)(w + take((size_t)NEDGES * 4));
  float* t0     = (float*)(w + take((size_t)NNODES * FNODE * 4));
  float* bufA   = (float*)(w + take((size_t)NNODES * HIDD * 4));
  float* bufB   = (float*)(w + take((size_t)NNODES * HIDD * 4));
  float* feats  = (float*)(w + take((size_t)NGRAPH * FEATD * 4));
  if (p > ws_size) return; // workspace too small -> visible failure

  // CSR by dst
  k_zero_i32<<<(NNODES + 1 + 255) / 256, 256, 0, stream>>>(off, NNODES + 1);
  k_hist<<<(NEDGES + 255) / 256, 256, 0, stream>>>(edst, off);
  int n_scan = NNODES + 1;
  int nb_scan = (n_scan + 1023) / 1024;
  k_scan1<<<nb_scan, 1024, 0, stream>>>(off, n_scan, sums);
  k_scan2<<<1, 1, 0, stream>>>(sums, nb_scan);
  k_scan3<<<nb_scan, 1024, 0, stream>>>(off, n_scan, sums);
  k_copy_i32<<<(NNODES + 255) / 256, 256, 0, stream>>>(off, cur, NNODES);
  k_scatter<<<(NEDGES + 255) / 256, 256, 0, stream>>>(esrc, edst, cur, csr_src, csr_eid);

  // layer 0
  k_edge32<<<NNODES / 4, 256, 0, stream>>>(x, ea, We0, off, csr_src, csr_eid, t0);
  k_gemm_relu<FNODE><<<(NNODES + 31) / 32, 256, 0, stream>>>(t0, W0, b0, bufA, NNODES);

  // layers 1..3 (ping-pong, GEMM in-place)
  const float* hin = bufA;
  float* tb[2] = {bufB, bufA};
  for (int l = 0; l < 3; ++l) {
    float* t = tb[l & 1];
    k_edge256<<<NNODES / 4, 256, 0, stream>>>(hin, ea, We + (size_t)l * FEDGE * HIDD, off,
                                              csr_src, csr_eid, t);
    k_gemm_relu<HIDD><<<(NNODES + 31) / 32, 256, 0, stream>>>(
        t, W + (size_t)l * HIDD * HIDD, bb + (size_t)l * HIDD, t, NNODES);
    hin = t;
  }

  // pool + heads
  k_pool<<<NGRAPH, HIDD, 0, stream>>>(hin, batch, gf, feats);
  k_heads<<<NGRAPH, 64, 0, stream>>>(feats, Wp, bp, Wv, bv, (float*)d_out);
}